// Round 1
// baseline (577.344 us; speedup 1.0000x reference)
//
#include <hip/hip_runtime.h>

#define N_IN_CH 256
#define N_OUT_CH 64
#define TILE_R 128
#define KC 64

// --- Kernel 1: transpose W [64][256] -> WT [256][64] (k-major) ---
__global__ void wt_kernel(const float* __restrict__ W, float* __restrict__ WT) {
    int idx = blockIdx.x * blockDim.x + threadIdx.x;
    if (idx < N_OUT_CH * N_IN_CH) {
        int o = idx >> 8;      // / 256
        int k = idx & 255;
        WT[k * N_OUT_CH + o] = W[idx];
    }
}

// --- Kernel 2: Xp = X @ W^T, fp32, LDS-tiled, 8x4 register tile ---
__global__ __launch_bounds__(256) void gemm_kernel(const float* __restrict__ X,
        const float* __restrict__ WT, float* __restrict__ Xp, int nrows) {
    __shared__ float Xs[TILE_R][KC + 4];   // row-major X chunk, +4 pad
    __shared__ float Ws[KC][N_OUT_CH];     // k-major W chunk

    const int tid = threadIdx.x;
    const int row0 = blockIdx.x * TILE_R;
    const int tx = tid & 15;   // channel group: channels tx*4 .. tx*4+3
    const int ty = tid >> 4;   // row group: rows ty*8 .. ty*8+7

    float acc[8][4];
    #pragma unroll
    for (int i = 0; i < 8; ++i)
        #pragma unroll
        for (int j = 0; j < 4; ++j) acc[i][j] = 0.f;

    for (int kc = 0; kc < N_IN_CH; kc += KC) {
        // stage X chunk: 128 rows x 64 floats = 2048 float4, 8 per thread
        #pragma unroll
        for (int it = 0; it < 8; ++it) {
            int f = it * 256 + tid;      // 0..2047
            int r = f >> 4;
            int kq = f & 15;
            int gr = row0 + r;
            float4 v = make_float4(0.f, 0.f, 0.f, 0.f);
            if (gr < nrows)
                v = *(const float4*)&X[(size_t)gr * N_IN_CH + kc + kq * 4];
            *(float4*)&Xs[r][kq * 4] = v;
        }
        // stage W chunk: 64 k x 64 ch = 1024 float4, 4 per thread
        #pragma unroll
        for (int it = 0; it < 4; ++it) {
            int f = it * 256 + tid;
            int k = f >> 4;
            int cq = f & 15;
            *(float4*)&Ws[k][cq * 4] =
                *(const float4*)&WT[(size_t)(kc + k) * N_OUT_CH + cq * 4];
        }
        __syncthreads();

        #pragma unroll
        for (int k4 = 0; k4 < KC; k4 += 4) {
            float4 wb[4];
            #pragma unroll
            for (int j = 0; j < 4; ++j)
                wb[j] = *(const float4*)&Ws[k4 + j][tx * 4];
            #pragma unroll
            for (int i = 0; i < 8; ++i) {
                float4 a = *(const float4*)&Xs[ty * 8 + i][k4];
                #pragma unroll
                for (int j = 0; j < 4; ++j) {
                    acc[i][j] = fmaf(a.x, ((const float*)&wb[0])[j],
                                fmaf(a.y, ((const float*)&wb[1])[j],
                                fmaf(a.z, ((const float*)&wb[2])[j],
                                fmaf(a.w, ((const float*)&wb[3])[j], acc[i][j]))));
                }
            }
        }
        __syncthreads();
    }

    #pragma unroll
    for (int i = 0; i < 8; ++i) {
        int gr = row0 + ty * 8 + i;
        if (gr < nrows) {
            float4 v = make_float4(acc[i][0], acc[i][1], acc[i][2], acc[i][3]);
            *(float4*)&Xp[(size_t)gr * N_OUT_CH + tx * 4] = v;
        }
    }
}

// --- Kernel 3: COO SpMM scatter: out[row] += val * Xp[col], atomics ---
// 64 lanes = 64 channels per edge -> coalesced 256B gather + coalesced atomics
__global__ __launch_bounds__(256) void spmm_kernel(const int* __restrict__ rows,
        const int* __restrict__ cols, const float* __restrict__ vals,
        const float* __restrict__ Xp, float* __restrict__ out, int nnz) {
    int t = blockIdx.x * blockDim.x + threadIdx.x;
    int e = t >> 6;
    int c = t & 63;
    if (e < nnz) {
        int r = rows[e];
        int col = cols[e];
        float v = vals[e];
        atomicAdd(&out[(size_t)r * N_OUT_CH + c],
                  v * Xp[(size_t)col * N_OUT_CH + c]);
    }
}

extern "C" void kernel_launch(void* const* d_in, const int* in_sizes, int n_in,
                              void* d_out, int out_size, void* d_ws, size_t ws_size,
                              hipStream_t stream) {
    // inputs: g1, g2, X, W_lin, L_rows, L_cols, L_vals
    const float* X      = (const float*)d_in[2];
    const float* W      = (const float*)d_in[3];
    const int*   L_rows = (const int*)d_in[4];
    const int*   L_cols = (const int*)d_in[5];
    const float* L_vals = (const float*)d_in[6];
    float* out = (float*)d_out;

    const int nrows = in_sizes[2] / N_IN_CH;   // 100000
    const int nnz   = in_sizes[4];             // 1600000

    float* WT = (float*)d_ws;                               // 256*64*4 = 64 KB
    float* Xp = (float*)((char*)d_ws + 64 * 1024);          // 100000*64*4 = 25.6 MB

    // zero-init output (harness poisons with 0xAA)
    hipMemsetAsync(d_out, 0, (size_t)out_size * sizeof(float), stream);

    wt_kernel<<<(N_OUT_CH * N_IN_CH + 255) / 256, 256, 0, stream>>>(W, WT);
    gemm_kernel<<<(nrows + TILE_R - 1) / TILE_R, 256, 0, stream>>>(X, WT, Xp, nrows);

    long long total = (long long)nnz * 64;
    int nblk = (int)((total + 255) / 256);
    spmm_kernel<<<nblk, 256, 0, stream>>>(L_rows, L_cols, L_vals, Xp, out, nnz);
}